// Round 4
// baseline (113.993 us; speedup 1.0000x reference)
//
#include <hip/hip_runtime.h>

#define BLK 256
#define IPT 2                      // i-points per thread
#define ITILE (BLK * IPT)          // 512 i-points per block-row
#define JS 136                     // j-offsets per slice: 64*136 = 8704 = P/2 + ITILE

// Kernel 1: build combined (center, signed-normal) array; also zero d_out.
// comb[2*i] = (cx,cy,cz,nx); comb[2*i+1] = (ny,nz,0,0).
// Targets carry NEGATED normals so e_ss - 2 e_st + e_tt = one pairwise sum.
__global__ void dc_build_combined(const float* __restrict__ verts,
                                  const float* __restrict__ tnorm,
                                  const float* __restrict__ tcent,
                                  const int* __restrict__ idx,
                                  float4* __restrict__ comb,
                                  float* __restrict__ out,
                                  int N, int M) {
    int i = blockIdx.x * blockDim.x + threadIdx.x;
    if (i == 0) out[0] = 0.0f;
    int P = N + M;
    if (i >= P) return;
    if (i < N) {
        int i0 = idx[3 * i + 0];
        int i1 = idx[3 * i + 1];
        int i2 = idx[3 * i + 2];
        float ax = verts[3 * i0 + 0], ay = verts[3 * i0 + 1], az = verts[3 * i0 + 2];
        float bx = verts[3 * i1 + 0], by = verts[3 * i1 + 1], bz = verts[3 * i1 + 2];
        float cx = verts[3 * i2 + 0], cy = verts[3 * i2 + 1], cz = verts[3 * i2 + 2];
        float ux = ax - bx, uy = ay - by, uz = az - bz;
        float vx = cx - bx, vy = cy - by, vz = cz - bz;
        float nx = 0.5f * (uy * vz - uz * vy);
        float ny = 0.5f * (uz * vx - ux * vz);
        float nz = 0.5f * (ux * vy - uy * vx);
        float gx = (ax + bx + cx) * (1.0f / 3.0f);
        float gy = (ay + by + cy) * (1.0f / 3.0f);
        float gz = (az + bz + cz) * (1.0f / 3.0f);
        comb[2 * i + 0] = make_float4(gx, gy, gz, nx);
        comb[2 * i + 1] = make_float4(ny, nz, 0.0f, 0.0f);
    } else {
        int t = i - N;
        float tx = tcent[3 * t + 0], ty = tcent[3 * t + 1], tz = tcent[3 * t + 2];
        float nx = -tnorm[3 * t + 0], ny = -tnorm[3 * t + 1], nz = -tnorm[3 * t + 2];
        comb[2 * i + 0] = make_float4(tx, ty, tz, nx);
        comb[2 * i + 1] = make_float4(ny, nz, 0.0f, 0.0f);
    }
}

// Kernel 2: circular half-range symmetric sum, j-point in SGPRs.
// For each i: offsets cj in [0, P/2 + ITILE) rel. to block's i0; pair
// distance d = cj - (i - i0); weight w(0)=1, w(1..P/2-1)=2, w(P/2)=1, else 0.
// j index is blockIdx/loop-derived => uniform => compiler emits s_load
// (SMEM pipe), NO ds_read in the inner loop. Every block identical work.
__global__ __launch_bounds__(BLK, 8) void dc_pair_energy(
    const float4* __restrict__ comb, float* __restrict__ out, int P) {
    __shared__ float wsum[BLK / 64];

    int tid = threadIdx.x;
    int i0 = blockIdx.x * ITILE;
    int half = P >> 1;
    int cj0 = blockIdx.y * JS;
    // interior slice: every pair has d in [1, half-1] -> uniform weight 2
    bool pure = (cj0 >= ITILE) && (cj0 + JS - 1 <= half - 1);

    float4 A[IPT];
    float2 Bn[IPT];
    int    li[IPT];
#pragma unroll
    for (int k = 0; k < IPT; ++k) {
        li[k] = k * BLK + tid;
        int i = i0 + li[k];
        A[k] = comb[2 * i + 0];
        float4 b = comb[2 * i + 1];
        Bn[k] = make_float2(b.x, b.y);
    }
    float acc[IPT];
#pragma unroll
    for (int k = 0; k < IPT; ++k) acc[k] = 0.0f;

    int jbase = i0 + cj0;   // uniform

    if (pure) {
#pragma unroll 4
        for (int jj = 0; jj < JS; ++jj) {
            int jr = jbase + jj;
            int jm = (jr >= P) ? jr - P : jr;      // uniform select
            float4 a = comb[2 * jm + 0];           // uniform addr -> s_load
            float4 b = comb[2 * jm + 1];           // merges to s_load_dwordx8
#pragma unroll
            for (int k = 0; k < IPT; ++k) {
                float dx = A[k].x - a.x;
                float dy = A[k].y - a.y;
                float dz = A[k].z - a.z;
                float d2p = fmaf(dx, dx, fmaf(dy, dy, fmaf(dz, dz, 1.0f)));
                float rk = __builtin_amdgcn_rcpf(d2p);
                float dot = fmaf(A[k].w, a.w, fmaf(Bn[k].x, b.x, Bn[k].y * b.y));
                acc[k] = fmaf(rk, dot, acc[k]);
            }
        }
#pragma unroll
        for (int k = 0; k < IPT; ++k) acc[k] *= 2.0f;   // interior weight
    } else {
#pragma unroll 4
        for (int jj = 0; jj < JS; ++jj) {
            int jr = jbase + jj;
            int jm = (jr >= P) ? jr - P : jr;
            float4 a = comb[2 * jm + 0];
            float4 b = comb[2 * jm + 1];
            int cj = cj0 + jj;
#pragma unroll
            for (int k = 0; k < IPT; ++k) {
                int d = cj - li[k];
                float w = ((unsigned)(d - 1) < (unsigned)(half - 1)) ? 2.0f
                        : ((d == 0 || d == half) ? 1.0f : 0.0f);
                float dx = A[k].x - a.x;
                float dy = A[k].y - a.y;
                float dz = A[k].z - a.z;
                float d2p = fmaf(dx, dx, fmaf(dy, dy, fmaf(dz, dz, 1.0f)));
                float rk = __builtin_amdgcn_rcpf(d2p);
                float dot = fmaf(A[k].w, a.w, fmaf(Bn[k].x, b.x, Bn[k].y * b.y));
                acc[k] = fmaf(w * rk, dot, acc[k]);
            }
        }
    }

    float s = 0.0f;
#pragma unroll
    for (int k = 0; k < IPT; ++k) s += acc[k];
#pragma unroll
    for (int off = 32; off > 0; off >>= 1) s += __shfl_down(s, off, 64);
    if ((tid & 63) == 0) wsum[tid >> 6] = s;
    __syncthreads();
    if (tid == 0) {
        float t = 0.0f;
#pragma unroll
        for (int w = 0; w < BLK / 64; ++w) t += wsum[w];
        atomicAdd(out, t);
    }
}

extern "C" void kernel_launch(void* const* d_in, const int* in_sizes, int n_in,
                              void* d_out, int out_size, void* d_ws, size_t ws_size,
                              hipStream_t stream) {
    const float* verts = (const float*)d_in[0];   // (V,3) f32
    const float* tnorm = (const float*)d_in[1];   // (M,3) f32
    const float* tcent = (const float*)d_in[2];   // (M,3) f32
    const int*   sidx  = (const int*)d_in[3];     // (N,3) i32

    int M = in_sizes[1] / 3;
    int N = in_sizes[3] / 3;
    int P = N + M;                                // 16384

    float4* comb = (float4*)d_ws;                 // 2 float4/point = 512 KB
    float*  out  = (float*)d_out;

    int bblocks = (P + BLK - 1) / BLK;
    dc_build_combined<<<bblocks, BLK, 0, stream>>>(verts, tnorm, tcent, sidx,
                                                   comb, out, N, M);

    int nslice = (P / 2 + ITILE + JS - 1) / JS;   // 64 for P=16384
    dim3 grid(P / ITILE, nslice);                 // 32 x 64 = 2048 uniform blocks
    dc_pair_energy<<<grid, BLK, 0, stream>>>(comb, out, P);
}

// Round 5
// 99.492 us; speedup vs baseline: 1.1457x; 1.1457x over previous
//
#include <hip/hip_runtime.h>

typedef short bf16x8 __attribute__((ext_vector_type(8)));
typedef float f32x16 __attribute__((ext_vector_type(16)));

// round-to-nearest-even fp32 -> bf16 (bits)
static __device__ __forceinline__ unsigned short f2bf(float x) {
    unsigned u = __builtin_bit_cast(unsigned, x);
    unsigned r = (u + 0x7FFFu + ((u >> 16) & 1u)) >> 16;
    return (unsigned short)r;
}
static __device__ __forceinline__ float bf2f(unsigned short h) {
    unsigned u = (unsigned)h << 16;
    return __builtin_bit_cast(float, u);
}

// Kernel 1: per point p build MFMA K-vectors (bf16, hi/lo split) for two grams:
//   gram1: denom = 1 + s_i + s_j - 2<c_i,c_j>   (K slots: 9 cross + 2+2 s + 1 one)
//   gram2: dot   = <n_i,n_j>                    (9 cross slots)
// and scatter them into 32x32x16 A/B fragment layout:
//   A[m=lane&31][k=(lane>>5)*8+j]; point p -> tile=p>>5, m=p&31;
//   k0..7 chunk -> lane m, k8..15 chunk -> lane 32+m. 16B contiguous per chunk.
// Targets carry NEGATED normals (folds e_ss - 2 e_st + e_tt into one sum).
__global__ void dc_pack(const float* __restrict__ verts,
                        const float* __restrict__ tnorm,
                        const float* __restrict__ tcent,
                        const int* __restrict__ idx,
                        unsigned short* __restrict__ ws,
                        float* __restrict__ out,
                        int N, int M) {
    int p = blockIdx.x * blockDim.x + threadIdx.x;
    if (p == 0) out[0] = 0.0f;
    int P = N + M;
    if (p >= P) return;

    float cx, cy, cz, nx, ny, nz;
    if (p < N) {
        int i0 = idx[3 * p + 0], i1 = idx[3 * p + 1], i2 = idx[3 * p + 2];
        float ax = verts[3 * i0], ay = verts[3 * i0 + 1], az = verts[3 * i0 + 2];
        float bx = verts[3 * i1], by = verts[3 * i1 + 1], bz = verts[3 * i1 + 2];
        float qx = verts[3 * i2], qy = verts[3 * i2 + 1], qz = verts[3 * i2 + 2];
        float ux = ax - bx, uy = ay - by, uz = az - bz;
        float vx = qx - bx, vy = qy - by, vz = qz - bz;
        nx = 0.5f * (uy * vz - uz * vy);
        ny = 0.5f * (uz * vx - ux * vz);
        nz = 0.5f * (ux * vy - uy * vx);
        cx = (ax + bx + qx) * (1.0f / 3.0f);
        cy = (ay + by + qy) * (1.0f / 3.0f);
        cz = (az + bz + qz) * (1.0f / 3.0f);
    } else {
        int t = p - N;
        cx = tcent[3 * t]; cy = tcent[3 * t + 1]; cz = tcent[3 * t + 2];
        nx = -tnorm[3 * t]; ny = -tnorm[3 * t + 1]; nz = -tnorm[3 * t + 2];
    }

    // hi/lo bf16 splits
    unsigned short chx = f2bf(cx), chy = f2bf(cy), chz = f2bf(cz);
    unsigned short clx = f2bf(cx - bf2f(chx));
    unsigned short cly = f2bf(cy - bf2f(chy));
    unsigned short clz = f2bf(cz - bf2f(chz));
    unsigned short nhx = f2bf(nx), nhy = f2bf(ny), nhz = f2bf(nz);
    unsigned short nlx = f2bf(nx - bf2f(nhx));
    unsigned short nly = f2bf(ny - bf2f(nhy));
    unsigned short nlz = f2bf(nz - bf2f(nhz));
    // s = |c~|^2 of the REPRESENTED point (hi+lo), split hi/lo
    float ex = bf2f(chx) + bf2f(clx);
    float ey = bf2f(chy) + bf2f(cly);
    float ez = bf2f(chz) + bf2f(clz);
    float s = ex * ex + ey * ey + ez * ez;
    unsigned short sh = f2bf(s), sl = f2bf(s - bf2f(sh));
    // -2*hi / -2*lo : exact exponent shift
    unsigned short m2hx = f2bf(-2.0f * bf2f(chx)), m2hy = f2bf(-2.0f * bf2f(chy)), m2hz = f2bf(-2.0f * bf2f(chz));
    unsigned short m2lx = f2bf(-2.0f * bf2f(clx)), m2ly = f2bf(-2.0f * bf2f(cly)), m2lz = f2bf(-2.0f * bf2f(clz));
    const unsigned short one = 0x3F80;  // bf16(1.0)

    // K-vectors. cross terms: A=[-2h,-2h,-2l] pairs B=[h,l,h] => hh+hl+lh.
    __align__(16) unsigned short A1v[16] = {
        m2hx, m2hy, m2hz,  m2hx, m2hy, m2hz,  m2lx, m2ly, m2lz,
        sh, sl,  one, one,  one,  0, 0 };
    __align__(16) unsigned short B1v[16] = {
        chx, chy, chz,  clx, cly, clz,  chx, chy, chz,
        one, one,  sh, sl,  one,  0, 0 };
    __align__(16) unsigned short A2v[16] = {
        nhx, nhy, nhz,  nhx, nhy, nhz,  nlx, nly, nlz,
        0, 0, 0, 0, 0, 0, 0 };
    __align__(16) unsigned short B2v[16] = {
        nhx, nhy, nhz,  nlx, nly, nlz,  nhx, nhy, nhz,
        0, 0, 0, 0, 0, 0, 0 };

    size_t arr = (size_t)P * 16;                   // ushorts per frag array
    unsigned short* A1 = ws;
    unsigned short* B1 = ws + arr;
    unsigned short* A2 = ws + 2 * arr;
    unsigned short* B2 = ws + 3 * arr;

    int tile = p >> 5, m = p & 31;
    size_t lo = ((size_t)tile * 64 + m) * 8;       // k0..7 -> lane m
    size_t hi = lo + 32 * 8;                       // k8..15 -> lane 32+m

    *(uint4*)(A1 + lo) = *(const uint4*)&A1v[0];
    *(uint4*)(A1 + hi) = *(const uint4*)&A1v[8];
    *(uint4*)(B1 + lo) = *(const uint4*)&B1v[0];
    *(uint4*)(B1 + hi) = *(const uint4*)&B1v[8];
    *(uint4*)(A2 + lo) = *(const uint4*)&A2v[0];
    *(uint4*)(A2 + hi) = *(const uint4*)&A2v[8];
    *(uint4*)(B2 + lo) = *(const uint4*)&B2v[0];
    *(uint4*)(B2 + hi) = *(const uint4*)&B2v[8];
}

// Kernel 2: full-matrix tile sweep. Wave owns one I row-tile (A frags in regs),
// loops 64 J tiles: 2 MFMAs (denom, dot) then elementwise rcp+fmac on acc regs.
// Sum is invariant to within-tile row/col permutation, so only A/B K-alignment
// matters (symmetric by construction).
__global__ __launch_bounds__(256, 4) void dc_pair_mfma(
    const unsigned short* __restrict__ ws, float* __restrict__ out,
    int P, int nJpw) {
    __shared__ float wsum[4];

    size_t arr = (size_t)P * 16;
    const unsigned short* A1 = ws;
    const unsigned short* B1 = ws + arr;
    const unsigned short* A2 = ws + 2 * arr;
    const unsigned short* B2 = ws + 3 * arr;

    int tid = threadIdx.x;
    int lane = tid & 63, wv = tid >> 6;
    int I = blockIdx.x >> 1;
    int j0 = (blockIdx.x & 1) * (4 * nJpw) + wv * nJpw;

    bf16x8 a1 = *(const bf16x8*)(A1 + ((size_t)I * 64 + lane) * 8);
    bf16x8 a2 = *(const bf16x8*)(A2 + ((size_t)I * 64 + lane) * 8);

    f32x16 zero = {0.f,0.f,0.f,0.f,0.f,0.f,0.f,0.f,0.f,0.f,0.f,0.f,0.f,0.f,0.f,0.f};
    f32x16 part = zero;

    const unsigned short* pb1 = B1 + ((size_t)j0 * 64 + lane) * 8;
    const unsigned short* pb2 = B2 + ((size_t)j0 * 64 + lane) * 8;

#pragma unroll 2
    for (int j = 0; j < nJpw; ++j) {
        bf16x8 b1 = *(const bf16x8*)pb1;
        bf16x8 b2 = *(const bf16x8*)pb2;
        pb1 += 512; pb2 += 512;                       // next J tile (64 lanes * 8)
        f32x16 d1 = __builtin_amdgcn_mfma_f32_32x32x16_bf16(a1, b1, zero, 0, 0, 0);
        f32x16 d2 = __builtin_amdgcn_mfma_f32_32x32x16_bf16(a2, b2, zero, 0, 0, 0);
#pragma unroll
        for (int r = 0; r < 16; ++r)
            part[r] = fmaf(__builtin_amdgcn_rcpf(d1[r]), d2[r], part[r]);
    }

    float s = 0.0f;
#pragma unroll
    for (int r = 0; r < 16; ++r) s += part[r];
#pragma unroll
    for (int off = 32; off > 0; off >>= 1) s += __shfl_down(s, off, 64);
    if (lane == 0) wsum[wv] = s;
    __syncthreads();
    if (tid == 0) {
        float t = wsum[0] + wsum[1] + wsum[2] + wsum[3];
        atomicAdd(out, t);
    }
}

extern "C" void kernel_launch(void* const* d_in, const int* in_sizes, int n_in,
                              void* d_out, int out_size, void* d_ws, size_t ws_size,
                              hipStream_t stream) {
    const float* verts = (const float*)d_in[0];   // (V,3) f32
    const float* tnorm = (const float*)d_in[1];   // (M,3) f32
    const float* tcent = (const float*)d_in[2];   // (M,3) f32
    const int*   sidx  = (const int*)d_in[3];     // (N,3) i32

    int M = in_sizes[1] / 3;
    int N = in_sizes[3] / 3;
    int P = N + M;                                // 16384

    unsigned short* ws = (unsigned short*)d_ws;   // 4 frag arrays * 512 KB = 2 MB
    float* out = (float*)d_out;

    int bblocks = (P + 255) / 256;
    dc_pack<<<bblocks, 256, 0, stream>>>(verts, tnorm, tcent, sidx, ws, out, N, M);

    int nI = P / 32;                              // 512 row tiles
    int nJpw = nI / 8;                            // 64 J-tiles per wave
    dc_pair_mfma<<<nI * 2, 256, 0, stream>>>(ws, out, P, nJpw);
}